// Round 1
// baseline (3317.472 us; speedup 1.0000x reference)
//
#include <hip/hip_runtime.h>

#define SEQ    59
#define FEAT   64
#define VOCAB  578
#define BATCH  4096
#define UNITS  1024
#define KLSTM  1088   // FEAT + UNITS
#define NPAD   640    // VOCAB padded to 5*128

typedef __bf16 bf16x8 __attribute__((ext_vector_type(8)));
typedef __bf16 bf16x4 __attribute__((ext_vector_type(4)));
typedef float  floatx4 __attribute__((ext_vector_type(4)));

typedef const __attribute__((address_space(1))) char gas_char;
typedef __attribute__((address_space(3))) char las_char;

__device__ __forceinline__ float sigmoid_f(float x) { return 1.f / (1.f + __expf(-x)); }
__device__ __forceinline__ float tanh_f(float x) { float e = __expf(2.f * x); return 1.f - 2.f / (e + 1.f); }

// ---------------- conversion kernels ----------------

// x [B][SEQ][FEAT] fp32 -> bf16, vectorized x4
__global__ void convert_x_kernel(const float* __restrict__ x, __bf16* __restrict__ xbf) {
    int i = blockIdx.x * 256 + threadIdx.x;
    const int total = BATCH * SEQ * FEAT / 4;
    if (i >= total) return;
    float4 v = ((const float4*)x)[i];
    bf16x4 o;
    o.x = (__bf16)v.x; o.y = (__bf16)v.y; o.z = (__bf16)v.z; o.w = (__bf16)v.w;
    ((bf16x4*)xbf)[i] = o;
}

// Build Wtp [4096 rows][1088 k] bf16, row-major.
// Row permutation: np = ublk*128 + gate*32 + j  <->  n = gate*1024 + ublk*32 + j
// k < 64: from kernel[k][n]; else rec_kernel[k-64][n].
__global__ void convert_weights_kernel(const float* __restrict__ kern,
                                       const float* __restrict__ reck,
                                       __bf16* __restrict__ Wtp) {
    int idx = blockIdx.x * 256 + threadIdx.x;
    if (idx >= 4096 * KLSTM) return;
    int np = idx / KLSTM;
    int k  = idx - np * KLSTM;
    int ublk = np >> 7;
    int g    = (np >> 5) & 3;
    int j    = np & 31;
    int n    = g * 1024 + ublk * 32 + j;
    float v = (k < FEAT) ? kern[(size_t)k * 4096 + n]
                         : reck[(size_t)(k - FEAT) * 4096 + n];
    Wtp[idx] = (__bf16)v;
}

// Wt2p [640 n][1024 k] bf16 (n >= 578 zero-padded), from w2 [1024][578]
__global__ void convert_w2_kernel(const float* __restrict__ w2, __bf16* __restrict__ Wt2p) {
    int idx = blockIdx.x * 256 + threadIdx.x;
    if (idx >= NPAD * 1024) return;
    int n = idx >> 10;
    int k = idx & 1023;
    float v = (n < VOCAB) ? w2[(size_t)k * VOCAB + n] : 0.f;
    Wt2p[idx] = (__bf16)v;
}

// ---------------- LSTM step: [4096,1088] @ [1088,4096] + fused gates ----------------
// Block: 128 batch-rows x 32 units x 4 gates (=128 cols of Wtp'). 256 thr = 4 waves (2x2).
// K-loop: 17 iters of BK=64; iter 0 = x columns, iters 1..16 = h columns.
__global__ void __launch_bounds__(256) lstm_step_kernel(
    const __bf16* __restrict__ xbf,
    const __bf16* __restrict__ Wtp,
    const float*  __restrict__ bias,
    const __bf16* __restrict__ hin,
    __bf16*       __restrict__ hout,
    float*        __restrict__ cstate,
    int t)
{
    __shared__ __bf16 As[128 * 64];
    __shared__ __bf16 Bs[128 * 64];

    const int tid  = threadIdx.x;
    const int wid  = tid >> 6;
    const int lane = tid & 63;
    const int ln   = lane & 15;
    const int lk   = lane >> 4;
    const int wm   = wid >> 1;
    const int wn   = wid & 1;
    const int rb   = blockIdx.x;
    const int ub   = blockIdx.y;

    floatx4 acc[4][4];
#pragma unroll
    for (int m = 0; m < 4; ++m)
#pragma unroll
        for (int g = 0; g < 4; ++g)
            acc[m][g] = (floatx4){0.f, 0.f, 0.f, 0.f};

    // XOR-swizzled staging: LDS chunk slot (row, kgs) holds global chunk (row, kgs ^ (row&7))
    int s_row[4], s_kgd[4];
#pragma unroll
    for (int q = 0; q < 4; ++q) {
        int flat = q * 256 + tid;
        int row  = flat >> 3;
        s_row[q] = row;
        s_kgd[q] = (flat & 7) ^ (row & 7);
    }

    for (int kt = 0; kt < 17; ++kt) {
        __syncthreads();
        // stage A (128 rows x 64 k)
#pragma unroll
        for (int q = 0; q < 4; ++q) {
            const int row = s_row[q], kgd = s_kgd[q];
            const __bf16* gp;
            if (kt == 0)
                gp = xbf + (size_t)(rb * 128 + row) * (SEQ * FEAT) + t * FEAT + kgd * 8;
            else
                gp = hin + ((size_t)(rb * 128 + row) << 10) + (kt - 1) * 64 + kgd * 8;
            __builtin_amdgcn_global_load_lds((gas_char*)gp,
                (las_char*)(As + (size_t)(q * 256 + (wid << 6)) * 8), 16, 0, 0);
        }
        // stage B (128 n-rows x 64 k)
#pragma unroll
        for (int q = 0; q < 4; ++q) {
            const int n = s_row[q], kgd = s_kgd[q];
            const __bf16* gp = Wtp + (size_t)(ub * 128 + n) * KLSTM + kt * 64 + kgd * 8;
            __builtin_amdgcn_global_load_lds((gas_char*)gp,
                (las_char*)(Bs + (size_t)(q * 256 + (wid << 6)) * 8), 16, 0, 0);
        }
        __syncthreads();
        // compute
#pragma unroll
        for (int kk = 0; kk < 2; ++kk) {
            const int kg = kk * 4 + lk;
            bf16x8 a[4], b[4];
#pragma unroll
            for (int m = 0; m < 4; ++m) {
                int row  = wm * 64 + m * 16 + ln;
                int ccol = (kg ^ (row & 7)) * 8;
                a[m] = *(const bf16x8*)(As + row * 64 + ccol);
            }
#pragma unroll
            for (int g = 0; g < 4; ++g) {
                int n    = g * 32 + wn * 16 + ln;
                int ccol = (kg ^ (n & 7)) * 8;
                b[g] = *(const bf16x8*)(Bs + n * 64 + ccol);
            }
#pragma unroll
            for (int m = 0; m < 4; ++m)
#pragma unroll
                for (int g = 0; g < 4; ++g)
                    acc[m][g] = __builtin_amdgcn_mfma_f32_16x16x32_bf16(a[m], b[g], acc[m][g], 0, 0, 0);
        }
    }

    // fused LSTM epilogue: lane owns unit u across all 4 gates (different acc frags)
    const int u  = ub * 32 + wn * 16 + ln;
    const float bi  = bias[u];
    const float bfv = bias[UNITS + u];
    const float bg  = bias[2 * UNITS + u];
    const float bo  = bias[3 * UNITS + u];
#pragma unroll
    for (int m = 0; m < 4; ++m) {
        const int row0 = rb * 128 + wm * 64 + m * 16 + lk * 4;
#pragma unroll
        for (int r = 0; r < 4; ++r) {
            const size_t idx = ((size_t)(row0 + r) << 10) + u;
            float ig = sigmoid_f(acc[m][0][r] + bi);
            float fg = sigmoid_f(acc[m][1][r] + bfv);
            float gg = tanh_f(acc[m][2][r] + bg);
            float og = sigmoid_f(acc[m][3][r] + bo);
            float cn = fg * cstate[idx] + ig * gg;
            cstate[idx] = cn;
            hout[idx] = (__bf16)(og * tanh_f(cn));
        }
    }
}

// ---------------- final dense: [4096,1024] @ [1024,640] -> logits fp32 ----------------
__global__ void __launch_bounds__(256) dense_kernel(
    const __bf16* __restrict__ hin,
    const __bf16* __restrict__ Wt2p,
    float*        __restrict__ logits)
{
    __shared__ __bf16 As[128 * 64];
    __shared__ __bf16 Bs[128 * 64];

    const int tid  = threadIdx.x;
    const int wid  = tid >> 6;
    const int lane = tid & 63;
    const int ln   = lane & 15;
    const int lk   = lane >> 4;
    const int wm   = wid >> 1;
    const int wn   = wid & 1;
    const int rb   = blockIdx.x;
    const int nb   = blockIdx.y;

    floatx4 acc[4][4];
#pragma unroll
    for (int m = 0; m < 4; ++m)
#pragma unroll
        for (int g = 0; g < 4; ++g)
            acc[m][g] = (floatx4){0.f, 0.f, 0.f, 0.f};

    int s_row[4], s_kgd[4];
#pragma unroll
    for (int q = 0; q < 4; ++q) {
        int flat = q * 256 + tid;
        int row  = flat >> 3;
        s_row[q] = row;
        s_kgd[q] = (flat & 7) ^ (row & 7);
    }

    for (int kt = 0; kt < 16; ++kt) {
        __syncthreads();
#pragma unroll
        for (int q = 0; q < 4; ++q) {
            const int row = s_row[q], kgd = s_kgd[q];
            const __bf16* gp = hin + ((size_t)(rb * 128 + row) << 10) + kt * 64 + kgd * 8;
            __builtin_amdgcn_global_load_lds((gas_char*)gp,
                (las_char*)(As + (size_t)(q * 256 + (wid << 6)) * 8), 16, 0, 0);
        }
#pragma unroll
        for (int q = 0; q < 4; ++q) {
            const int n = s_row[q], kgd = s_kgd[q];
            const __bf16* gp = Wt2p + ((size_t)(nb * 128 + n) << 10) + kt * 64 + kgd * 8;
            __builtin_amdgcn_global_load_lds((gas_char*)gp,
                (las_char*)(Bs + (size_t)(q * 256 + (wid << 6)) * 8), 16, 0, 0);
        }
        __syncthreads();
#pragma unroll
        for (int kk = 0; kk < 2; ++kk) {
            const int kg = kk * 4 + lk;
            bf16x8 a[4], b[4];
#pragma unroll
            for (int m = 0; m < 4; ++m) {
                int row  = wm * 64 + m * 16 + ln;
                int ccol = (kg ^ (row & 7)) * 8;
                a[m] = *(const bf16x8*)(As + row * 64 + ccol);
            }
#pragma unroll
            for (int g = 0; g < 4; ++g) {
                int n    = g * 32 + wn * 16 + ln;
                int ccol = (kg ^ (n & 7)) * 8;
                b[g] = *(const bf16x8*)(Bs + n * 64 + ccol);
            }
#pragma unroll
            for (int m = 0; m < 4; ++m)
#pragma unroll
                for (int g = 0; g < 4; ++g)
                    acc[m][g] = __builtin_amdgcn_mfma_f32_16x16x32_bf16(a[m], b[g], acc[m][g], 0, 0, 0);
        }
    }

#pragma unroll
    for (int m = 0; m < 4; ++m) {
        const int row0 = rb * 128 + wm * 64 + m * 16 + lk * 4;
#pragma unroll
        for (int g = 0; g < 4; ++g) {
            const int n = nb * 128 + g * 32 + wn * 16 + ln;
#pragma unroll
            for (int r = 0; r < 4; ++r)
                logits[(size_t)(row0 + r) * NPAD + n] = acc[m][g][r];
        }
    }
}

// ---------------- row softmax over 578 cols (+b2) ----------------
__global__ void __launch_bounds__(256) softmax_kernel(
    const float* __restrict__ logits,
    const float* __restrict__ b2,
    float* __restrict__ out)
{
    const int row = blockIdx.x;
    const int tid = threadIdx.x;
    __shared__ float red[8];

    float z[3];
    float lmax = -1e30f;
#pragma unroll
    for (int j = 0; j < 3; ++j) {
        int col = tid + j * 256;
        if (col < VOCAB) {
            z[j] = logits[(size_t)row * NPAD + col] + b2[col];
            lmax = fmaxf(lmax, z[j]);
        } else z[j] = -1e30f;
    }
    for (int off = 32; off > 0; off >>= 1) lmax = fmaxf(lmax, __shfl_xor(lmax, off));
    if ((tid & 63) == 0) red[tid >> 6] = lmax;
    __syncthreads();
    lmax = fmaxf(fmaxf(red[0], red[1]), fmaxf(red[2], red[3]));
    __syncthreads();

    float lsum = 0.f;
#pragma unroll
    for (int j = 0; j < 3; ++j) {
        int col = tid + j * 256;
        if (col < VOCAB) { z[j] = __expf(z[j] - lmax); lsum += z[j]; }
    }
    for (int off = 32; off > 0; off >>= 1) lsum += __shfl_xor(lsum, off);
    if ((tid & 63) == 0) red[tid >> 6] = lsum;
    __syncthreads();
    lsum = red[0] + red[1] + red[2] + red[3];
    float inv = 1.f / lsum;
#pragma unroll
    for (int j = 0; j < 3; ++j) {
        int col = tid + j * 256;
        if (col < VOCAB) out[(size_t)row * VOCAB + col] = z[j] * inv;
    }
}

// ---------------- launch ----------------
extern "C" void kernel_launch(void* const* d_in, const int* in_sizes, int n_in,
                              void* d_out, int out_size, void* d_ws, size_t ws_size,
                              hipStream_t stream)
{
    const float* x    = (const float*)d_in[0];
    const float* kern = (const float*)d_in[1];
    const float* reck = (const float*)d_in[2];
    const float* bias = (const float*)d_in[3];
    const float* w2   = (const float*)d_in[4];
    const float* b2   = (const float*)d_in[5];
    float* out = (float*)d_out;

    char* ws = (char*)d_ws;
    size_t off = 0;
    auto alloc = [&](size_t bytes) {
        char* p = ws + off;
        off += (bytes + 255) & ~(size_t)255;
        return p;
    };
    __bf16* Wtp    = (__bf16*)alloc((size_t)4096 * KLSTM * 2);
    __bf16* Wt2p   = (__bf16*)alloc((size_t)NPAD * 1024 * 2);
    __bf16* xbf    = (__bf16*)alloc((size_t)BATCH * SEQ * FEAT * 2);
    __bf16* h0     = (__bf16*)alloc((size_t)BATCH * UNITS * 2);
    __bf16* h1     = (__bf16*)alloc((size_t)BATCH * UNITS * 2);
    float*  cst    = (float*)alloc((size_t)BATCH * UNITS * 4);
    float*  logits = (float*)alloc((size_t)BATCH * NPAD * 4);
    if (off > ws_size) return;  // loud failure: output stays zero

    hipMemsetAsync(h0, 0, (size_t)BATCH * UNITS * 2, stream);
    hipMemsetAsync(cst, 0, (size_t)BATCH * UNITS * 4, stream);

    convert_x_kernel<<<(BATCH * SEQ * FEAT / 4 + 255) / 256, 256, 0, stream>>>(x, xbf);
    convert_weights_kernel<<<(4096 * KLSTM + 255) / 256, 256, 0, stream>>>(kern, reck, Wtp);
    convert_w2_kernel<<<(NPAD * 1024 + 255) / 256, 256, 0, stream>>>(w2, Wt2p);

    __bf16* hin = h0; __bf16* hout = h1;
    for (int t = 0; t < SEQ; ++t) {
        lstm_step_kernel<<<dim3(32, 32), 256, 0, stream>>>(xbf, Wtp, bias, hin, hout, cst, t);
        __bf16* tmp = hin; hin = hout; hout = tmp;
    }

    dense_kernel<<<dim3(32, 5), 256, 0, stream>>>(hin, Wt2p, logits);
    softmax_kernel<<<BATCH, 256, 0, stream>>>(logits, b2, out);
}

// Round 3
// 2577.860 us; speedup vs baseline: 1.2869x; 1.2869x over previous
//
#include <hip/hip_runtime.h>

#define SEQ    59
#define FEAT   64
#define VOCAB  578
#define BATCH  4096
#define UNITS  1024
#define KLSTM  1088   // FEAT + UNITS
#define NPAD   640    // VOCAB padded to 5*128

typedef __bf16 bf16x8 __attribute__((ext_vector_type(8)));
typedef __bf16 bf16x4 __attribute__((ext_vector_type(4)));
typedef float  floatx4 __attribute__((ext_vector_type(4)));

typedef const __attribute__((address_space(1))) char gas_char;
typedef __attribute__((address_space(3))) char las_char;

__device__ __forceinline__ float sigmoid_f(float x) { return 1.f / (1.f + __expf(-x)); }
__device__ __forceinline__ float tanh_f(float x) { float e = __expf(2.f * x); return 1.f - 2.f / (e + 1.f); }

// ---------------- conversion kernels ----------------

__global__ void convert_x_kernel(const float* __restrict__ x, __bf16* __restrict__ xbf) {
    int i = blockIdx.x * 256 + threadIdx.x;
    const int total = BATCH * SEQ * FEAT / 4;
    if (i >= total) return;
    float4 v = ((const float4*)x)[i];
    bf16x4 o;
    o.x = (__bf16)v.x; o.y = (__bf16)v.y; o.z = (__bf16)v.z; o.w = (__bf16)v.w;
    ((bf16x4*)xbf)[i] = o;
}

// Wtp [4096 rows][1088 k] bf16 row-major; row np = ublk*128 + gate*32 + j
__global__ void convert_weights_kernel(const float* __restrict__ kern,
                                       const float* __restrict__ reck,
                                       __bf16* __restrict__ Wtp) {
    int idx = blockIdx.x * 256 + threadIdx.x;
    if (idx >= 4096 * KLSTM) return;
    int np = idx / KLSTM;
    int k  = idx - np * KLSTM;
    int ublk = np >> 7;
    int g    = (np >> 5) & 3;
    int j    = np & 31;
    int n    = g * 1024 + ublk * 32 + j;
    float v = (k < FEAT) ? kern[(size_t)k * 4096 + n]
                         : reck[(size_t)(k - FEAT) * 4096 + n];
    Wtp[idx] = (__bf16)v;
}

__global__ void convert_w2_kernel(const float* __restrict__ w2, __bf16* __restrict__ Wt2p) {
    int idx = blockIdx.x * 256 + threadIdx.x;
    if (idx >= NPAD * 1024) return;
    int n = idx >> 10;
    int k = idx & 1023;
    float v = (n < VOCAB) ? w2[(size_t)k * VOCAB + n] : 0.f;
    Wt2p[idx] = (__bf16)v;
}

// ---------------- LSTM step: 128 batch x 256 gate-cols per block ----------------
// 256 thr = 4 waves (2 wm x 2 wn). Each block: A tile 128x64 + TWO B tiles 128x64.
// A-fragments reused across both B tiles -> ds_read:MFMA = 12:32 per kk.
// Grid 32 x 16 = 512 blocks = exactly 2/CU (2 waves/SIMD at ~200 regs) -> no tail.
__global__ void __launch_bounds__(256, 2) lstm_step_kernel(
    const __bf16* __restrict__ xbf,
    const __bf16* __restrict__ Wtp,
    const float*  __restrict__ bias,
    const __bf16* __restrict__ hin,
    __bf16*       __restrict__ hout,
    float*        __restrict__ cstate,
    int t)
{
    __shared__ __bf16 As[128 * 64];
    __shared__ __bf16 Bs[2][128 * 64];

    const int tid  = threadIdx.x;
    const int wid  = tid >> 6;
    const int lane = tid & 63;
    const int ln   = lane & 15;
    const int lk   = lane >> 4;
    const int wm   = wid >> 1;
    const int wn   = wid & 1;
    const int rb   = blockIdx.x;
    const int yb   = blockIdx.y;   // ub-pair: ublk {2*yb, 2*yb+1}

    floatx4 acc[2][4][4];
#pragma unroll
    for (int p = 0; p < 2; ++p)
#pragma unroll
        for (int m = 0; m < 4; ++m)
#pragma unroll
            for (int g = 0; g < 4; ++g)
                acc[p][m][g] = (floatx4){0.f, 0.f, 0.f, 0.f};

    // XOR-swizzled staging: LDS chunk slot (row, kgs) holds global chunk (row, kgs ^ (row&7))
    int s_row[4], s_kgd[4];
#pragma unroll
    for (int q = 0; q < 4; ++q) {
        int flat = q * 256 + tid;
        int row  = flat >> 3;
        s_row[q] = row;
        s_kgd[q] = (flat & 7) ^ (row & 7);
    }

    for (int kt = 0; kt < 17; ++kt) {
        __syncthreads();
        // stage A (128 batch-rows x 64 k)
#pragma unroll
        for (int q = 0; q < 4; ++q) {
            const int row = s_row[q], kgd = s_kgd[q];
            const __bf16* gp;
            if (kt == 0)
                gp = xbf + (size_t)(rb * 128 + row) * (SEQ * FEAT) + t * FEAT + kgd * 8;
            else
                gp = hin + ((size_t)(rb * 128 + row) << 10) + (kt - 1) * 64 + kgd * 8;
            __builtin_amdgcn_global_load_lds((gas_char*)gp,
                (las_char*)(As + (size_t)(q * 256 + (wid << 6)) * 8), 16, 0, 0);
        }
        // stage B tiles p=0,1 (Wtp rows yb*256 + p*128 + n)
#pragma unroll
        for (int p = 0; p < 2; ++p) {
#pragma unroll
            for (int q = 0; q < 4; ++q) {
                const int n = s_row[q], kgd = s_kgd[q];
                const __bf16* gp = Wtp + (size_t)(yb * 256 + p * 128 + n) * KLSTM + kt * 64 + kgd * 8;
                __builtin_amdgcn_global_load_lds((gas_char*)gp,
                    (las_char*)(Bs[p] + (size_t)(q * 256 + (wid << 6)) * 8), 16, 0, 0);
            }
        }
        __syncthreads();
        // compute
#pragma unroll
        for (int kk = 0; kk < 2; ++kk) {
            const int kg = kk * 4 + lk;
            bf16x8 a[4], b0[4], b1[4];
#pragma unroll
            for (int m = 0; m < 4; ++m) {
                int row  = wm * 64 + m * 16 + ln;
                int ccol = (kg ^ (row & 7)) * 8;
                a[m] = *(const bf16x8*)(As + row * 64 + ccol);
            }
#pragma unroll
            for (int g = 0; g < 4; ++g) {
                int n    = g * 32 + wn * 16 + ln;
                int ccol = (kg ^ (n & 7)) * 8;
                b0[g] = *(const bf16x8*)(Bs[0] + n * 64 + ccol);
                b1[g] = *(const bf16x8*)(Bs[1] + n * 64 + ccol);
            }
#pragma unroll
            for (int m = 0; m < 4; ++m)
#pragma unroll
                for (int g = 0; g < 4; ++g) {
                    acc[0][m][g] = __builtin_amdgcn_mfma_f32_16x16x32_bf16(a[m], b0[g], acc[0][m][g], 0, 0, 0);
                    acc[1][m][g] = __builtin_amdgcn_mfma_f32_16x16x32_bf16(a[m], b1[g], acc[1][m][g], 0, 0, 0);
                }
        }
    }

    // fused LSTM epilogue: lane owns unit u (per tile p) across all 4 gates
#pragma unroll
    for (int p = 0; p < 2; ++p) {
        const int u  = (yb * 2 + p) * 32 + wn * 16 + ln;
        const float bi  = bias[u];
        const float bfv = bias[UNITS + u];
        const float bg  = bias[2 * UNITS + u];
        const float bo  = bias[3 * UNITS + u];
#pragma unroll
        for (int m = 0; m < 4; ++m) {
            const int row0 = rb * 128 + wm * 64 + m * 16 + lk * 4;
#pragma unroll
            for (int r = 0; r < 4; ++r) {
                const size_t idx = ((size_t)(row0 + r) << 10) + u;
                float ig = sigmoid_f(acc[p][m][0][r] + bi);
                float fg = sigmoid_f(acc[p][m][1][r] + bfv);
                float gg = tanh_f(acc[p][m][2][r] + bg);
                float og = sigmoid_f(acc[p][m][3][r] + bo);
                float cn = fg * cstate[idx] + ig * gg;
                cstate[idx] = cn;
                hout[idx] = (__bf16)(og * tanh_f(cn));
            }
        }
    }
}

// ---------------- final dense: [4096,1024] @ [1024,640] -> logits fp32 ----------------
__global__ void __launch_bounds__(256) dense_kernel(
    const __bf16* __restrict__ hin,
    const __bf16* __restrict__ Wt2p,
    float*        __restrict__ logits)
{
    __shared__ __bf16 As[128 * 64];
    __shared__ __bf16 Bs[128 * 64];

    const int tid  = threadIdx.x;
    const int wid  = tid >> 6;
    const int lane = tid & 63;
    const int ln   = lane & 15;
    const int lk   = lane >> 4;
    const int wm   = wid >> 1;
    const int wn   = wid & 1;
    const int rb   = blockIdx.x;
    const int nb   = blockIdx.y;

    floatx4 acc[4][4];
#pragma unroll
    for (int m = 0; m < 4; ++m)
#pragma unroll
        for (int g = 0; g < 4; ++g)
            acc[m][g] = (floatx4){0.f, 0.f, 0.f, 0.f};

    int s_row[4], s_kgd[4];
#pragma unroll
    for (int q = 0; q < 4; ++q) {
        int flat = q * 256 + tid;
        int row  = flat >> 3;
        s_row[q] = row;
        s_kgd[q] = (flat & 7) ^ (row & 7);
    }

    for (int kt = 0; kt < 16; ++kt) {
        __syncthreads();
#pragma unroll
        for (int q = 0; q < 4; ++q) {
            const int row = s_row[q], kgd = s_kgd[q];
            const __bf16* gp = hin + ((size_t)(rb * 128 + row) << 10) + kt * 64 + kgd * 8;
            __builtin_amdgcn_global_load_lds((gas_char*)gp,
                (las_char*)(As + (size_t)(q * 256 + (wid << 6)) * 8), 16, 0, 0);
        }
#pragma unroll
        for (int q = 0; q < 4; ++q) {
            const int n = s_row[q], kgd = s_kgd[q];
            const __bf16* gp = Wt2p + ((size_t)(nb * 128 + n) << 10) + kt * 64 + kgd * 8;
            __builtin_amdgcn_global_load_lds((gas_char*)gp,
                (las_char*)(Bs + (size_t)(q * 256 + (wid << 6)) * 8), 16, 0, 0);
        }
        __syncthreads();
#pragma unroll
        for (int kk = 0; kk < 2; ++kk) {
            const int kg = kk * 4 + lk;
            bf16x8 a[4], b[4];
#pragma unroll
            for (int m = 0; m < 4; ++m) {
                int row  = wm * 64 + m * 16 + ln;
                int ccol = (kg ^ (row & 7)) * 8;
                a[m] = *(const bf16x8*)(As + row * 64 + ccol);
            }
#pragma unroll
            for (int g = 0; g < 4; ++g) {
                int n    = g * 32 + wn * 16 + ln;
                int ccol = (kg ^ (n & 7)) * 8;
                b[g] = *(const bf16x8*)(Bs + n * 64 + ccol);
            }
#pragma unroll
            for (int m = 0; m < 4; ++m)
#pragma unroll
                for (int g = 0; g < 4; ++g)
                    acc[m][g] = __builtin_amdgcn_mfma_f32_16x16x32_bf16(a[m], b[g], acc[m][g], 0, 0, 0);
        }
    }

#pragma unroll
    for (int m = 0; m < 4; ++m) {
        const int row0 = rb * 128 + wm * 64 + m * 16 + lk * 4;
#pragma unroll
        for (int g = 0; g < 4; ++g) {
            const int n = nb * 128 + g * 32 + wn * 16 + ln;
#pragma unroll
            for (int r = 0; r < 4; ++r)
                logits[(size_t)(row0 + r) * NPAD + n] = acc[m][g][r];
        }
    }
}

// ---------------- row softmax over 578 cols (+b2) ----------------
__global__ void __launch_bounds__(256) softmax_kernel(
    const float* __restrict__ logits,
    const float* __restrict__ b2,
    float* __restrict__ out)
{
    const int row = blockIdx.x;
    const int tid = threadIdx.x;
    __shared__ float red[8];

    float z[3];
    float lmax = -1e30f;
#pragma unroll
    for (int j = 0; j < 3; ++j) {
        int col = tid + j * 256;
        if (col < VOCAB) {
            z[j] = logits[(size_t)row * NPAD + col] + b2[col];
            lmax = fmaxf(lmax, z[j]);
        } else z[j] = -1e30f;
    }
    for (int off = 32; off > 0; off >>= 1) lmax = fmaxf(lmax, __shfl_xor(lmax, off));
    if ((tid & 63) == 0) red[tid >> 6] = lmax;
    __syncthreads();
    lmax = fmaxf(fmaxf(red[0], red[1]), fmaxf(red[2], red[3]));
    __syncthreads();

    float lsum = 0.f;
#pragma unroll
    for (int j = 0; j < 3; ++j) {
        int col = tid + j * 256;
        if (col < VOCAB) { z[j] = __expf(z[j] - lmax); lsum += z[j]; }
    }
    for (int off = 32; off > 0; off >>= 1) lsum += __shfl_xor(lsum, off);
    if ((tid & 63) == 0) red[tid >> 6] = lsum;
    __syncthreads();
    lsum = red[0] + red[1] + red[2] + red[3];
    float inv = 1.f / lsum;
#pragma unroll
    for (int j = 0; j < 3; ++j) {
        int col = tid + j * 256;
        if (col < VOCAB) out[(size_t)row * VOCAB + col] = z[j] * inv;
    }
}

// ---------------- launch ----------------
extern "C" void kernel_launch(void* const* d_in, const int* in_sizes, int n_in,
                              void* d_out, int out_size, void* d_ws, size_t ws_size,
                              hipStream_t stream)
{
    const float* x    = (const float*)d_in[0];
    const float* kern = (const float*)d_in[1];
    const float* reck = (const float*)d_in[2];
    const float* bias = (const float*)d_in[3];
    const float* w2   = (const float*)d_in[4];
    const float* b2   = (const float*)d_in[5];
    float* out = (float*)d_out;

    char* ws = (char*)d_ws;
    size_t off = 0;
    auto alloc = [&](size_t bytes) {
        char* p = ws + off;
        off += (bytes + 255) & ~(size_t)255;
        return p;
    };
    __bf16* Wtp    = (__bf16*)alloc((size_t)4096 * KLSTM * 2);
    __bf16* Wt2p   = (__bf16*)alloc((size_t)NPAD * 1024 * 2);
    __bf16* xbf    = (__bf16*)alloc((size_t)BATCH * SEQ * FEAT * 2);
    __bf16* h0     = (__bf16*)alloc((size_t)BATCH * UNITS * 2);
    __bf16* h1     = (__bf16*)alloc((size_t)BATCH * UNITS * 2);
    float*  cst    = (float*)alloc((size_t)BATCH * UNITS * 4);
    float*  logits = (float*)alloc((size_t)BATCH * NPAD * 4);
    if (off > ws_size) return;  // loud failure: output stays zero

    (void)hipMemsetAsync(h0, 0, (size_t)BATCH * UNITS * 2, stream);
    (void)hipMemsetAsync(cst, 0, (size_t)BATCH * UNITS * 4, stream);

    convert_x_kernel<<<(BATCH * SEQ * FEAT / 4 + 255) / 256, 256, 0, stream>>>(x, xbf);
    convert_weights_kernel<<<(4096 * KLSTM + 255) / 256, 256, 0, stream>>>(kern, reck, Wtp);
    convert_w2_kernel<<<(NPAD * 1024 + 255) / 256, 256, 0, stream>>>(w2, Wt2p);

    __bf16* hin = h0; __bf16* hout = h1;
    for (int t = 0; t < SEQ; ++t) {
        lstm_step_kernel<<<dim3(32, 16), 256, 0, stream>>>(xbf, Wtp, bias, hin, hout, cst, t);
        __bf16* tmp = hin; hin = hout; hout = tmp;
    }

    dense_kernel<<<dim3(32, 5), 256, 0, stream>>>(hin, Wt2p, logits);
    softmax_kernel<<<BATCH, 256, 0, stream>>>(logits, b2, out);
}